// Round 12
// baseline (90.087 us; speedup 1.0000x reference)
//
#include <hip/hip_runtime.h>
#include <math.h>

#define NROWS 8192
#define DDIM  128
#define K20   28.853900817779268f        // 20 * log2(e)
#define K2    (K20 * K20)                // 832.5476
#define DTHR  8.3255f                    // 0.01 * K2 : self-pair mask (real pairs >> this)

typedef _Float16 f16x8 __attribute__((ext_vector_type(8)));
typedef _Float16 f16x4 __attribute__((ext_vector_type(4)));
typedef _Float16 f16x2 __attribute__((ext_vector_type(2)));
typedef float    f32x4 __attribute__((ext_vector_type(4)));

typedef __attribute__((address_space(3))) uint32_t       lds_u32;
typedef const __attribute__((address_space(1))) uint32_t glb_u32;

#ifndef __has_builtin
#define __has_builtin(x) 0
#endif
#if __has_builtin(__builtin_amdgcn_fdot2)
#define HAVE_FDOT2 1
#else
#define HAVE_FDOT2 0
#endif

// Fragment-major layout for mfma_f32_16x16x32_f16 (16-row groups):
//   xf[g*2048 + kk*512 + l*8 + j] = x[i = g*16 + (l&15)][k = kk*32 + (l>>4)*8 + j]
// ws layout (floats after xf): sums[0..N) = nL (sum exp(-40d)), [N..2N) = nS (sum exp(-20d))

// ---- fp32 -> f16 frag-major transform + zero sums/out (verified R7/R8) ----
__global__ void convert_kernel(const float* __restrict__ x,
                               _Float16* __restrict__ xf,
                               float* __restrict__ sums,
                               float* __restrict__ out) {
    int idx = (blockIdx.x * 256 + threadIdx.x) * 4;    // flat (i,k) element index
    float4 v = *(const float4*)(x + idx);
    f16x4 h = { (_Float16)v.x, (_Float16)v.y, (_Float16)v.z, (_Float16)v.w };
    const int i = idx >> 7, k = idx & 127;             // k multiple of 4
    const int lane = (((k >> 3) & 3) << 4) | (i & 15);
    const int dst = (i >> 4) * 2048 + (k >> 5) * 512 + lane * 8 + (k & 7);
    *(f16x4*)(xf + dst) = h;
    if (threadIdx.x < 16) sums[blockIdx.x * 16 + threadIdx.x] = 0.0f;  // 1024*16 = 2*NROWS
    if (blockIdx.x == 0 && threadIdx.x == 0) out[0] = 0.0f;
}

// ---- LDS-staged pair kernel (canonical GEMM structure, full matrix).
//      Block = 128 rows (4 waves x 32-row strips) x 512-col segment, walked as
//      16 groups of 32 cols. Each 8 KB B-group is staged ONCE into LDS via
//      global_load_lds (width 16, double-buffered) and shared by all 4 waves:
//      4x less L1/L2 traffic than private VGPR streaming, and the per-wave
//      vmcnt-before-MFMA stall is replaced by one block-level barrier whose
//      drain targets loads issued a full compute-phase earlier. B never
//      transits VGPRs (keeps ~115 VGPR -> genuine 4 waves/SIMD). ----
__global__ __launch_bounds__(256, 4) void pair_kernel(
        const _Float16* __restrict__ xf,
        float* __restrict__ sums) {
    __shared__ _Float16 buf[2][4096];             // 2 x 8 KB B-group buffers

    const int tid = threadIdx.x;
    const int w = tid >> 6;
    const int lane = tid & 63;
    const int ig = blockIdx.x * 4 + w;            // 32-row strip, 0..255
    const int i0 = ig * 32;
    const int gc0 = blockIdx.y * 16;              // first 32-col group of segment

    // A fragments resident: 2 x 16-row frag sets x 4 k-chunks (1 KB loads)
    const _Float16* ab = xf + (size_t)(ig * 2) * 2048 + lane * 8;
    f16x8 a0[4], a1[4];
    #pragma unroll
    for (int kk = 0; kk < 4; ++kk) {
        a0[kk] = *(const f16x8*)(ab + kk * 512);
        a1[kk] = *(const f16x8*)(ab + 2048 + kk * 512);
    }

    float nL[8], nS[8];
    #pragma unroll
    for (int r = 0; r < 8; ++r) { nL[r] = 0.f; nS[r] = 0.f; }

    // stage one 8 KB B-group (gc = 32-col group index) into buf[bi]:
    // linear copy, 2 shots x (256 threads x 16 B); dest = uniform base + lane*16
    auto STAGE = [&](int bi, int gc) {
        const _Float16* s = xf + (size_t)gc * 4096 + tid * 8;
        __builtin_amdgcn_global_load_lds((glb_u32*)s,
                                         (lds_u32*)&buf[bi][tid * 8], 16, 0, 0);
        __builtin_amdgcn_global_load_lds((glb_u32*)(s + 2048),
                                         (lds_u32*)&buf[bi][2048 + tid * 8], 16, 0, 0);
    };

    // epilogue for one f32x4 accumulator quarter -> row sums base nX[q0..q0+3]
    auto EPI = [&](const f32x4 acc, int q0) {
        #pragma unroll
        for (int r = 0; r < 4; ++r) {
            float d2s = fmaf(-2.0f * K2, acc[r], 2.0f * K2);   // (20*log2e)^2 * d^2
            float ds  = __builtin_amdgcn_sqrtf(d2s);           // NaN on self, masked
            float tt  = __builtin_amdgcn_exp2f(-ds);           // exp(-20 d)
            tt = (d2s < DTHR) ? 0.0f : tt;                     // exact self exclusion
            nS[q0 + r] += tt;
            nL[q0 + r] = fmaf(tt, tt, nL[q0 + r]);             // exp(-40 d)
        }
    };

    // compute one 32x32 group from buf[bi]: two sequential 16-col halves
    // (b read just-in-time from LDS; acc liveness 8 regs per half)
    auto COMPUTE = [&](int bi) {
        #pragma unroll
        for (int h = 0; h < 2; ++h) {
            f32x4 acc0 = {0.f,0.f,0.f,0.f}, acc1 = {0.f,0.f,0.f,0.f};
            #pragma unroll
            for (int kk = 0; kk < 4; ++kk) {
                f16x8 b = *(const f16x8*)&buf[bi][h * 2048 + kk * 512 + lane * 8];
                acc0 = __builtin_amdgcn_mfma_f32_16x16x32_f16(a0[kk], b, acc0, 0, 0, 0);
                acc1 = __builtin_amdgcn_mfma_f32_16x16x32_f16(a1[kk], b, acc1, 0, 0, 0);
            }
            EPI(acc0, 0);   // rows i0      + q*4 + r  (both halves: same rows)
            EPI(acc1, 4);   // rows i0 + 16 + q*4 + r
        }
    };

    // pipeline: stage g+1 before computing g; one barrier per group.
    // The barrier's vmcnt drain targets loads issued a full COMPUTE earlier.
    STAGE(0, gc0);
    __syncthreads();
    for (int g = 0; g < 16; ++g) {
        if (g < 15) STAGE((g + 1) & 1, gc0 + g + 1);
        COMPUTE(g & 1);
        __syncthreads();   // (a) stage g+1 complete  (b) buf[g&1] free for reuse
    }

    // reduce across the 16 column-lanes; C/D map: col=lane&15,
    // row = i0 + s*16 + (lane>>4)*4 + r  (m89/m91, verified R7/R8)
    #pragma unroll
    for (int s = 0; s < 2; ++s) {
        #pragma unroll
        for (int r = 0; r < 4; ++r) {
            float aa = nL[s * 4 + r], ss = nS[s * 4 + r];
            #pragma unroll
            for (int m = 1; m < 16; m <<= 1) {
                aa += __shfl_xor(aa, m, 64);
                ss += __shfl_xor(ss, m, 64);
            }
            if ((lane & 15) == 0) {
                const int row = i0 + s * 16 + (lane >> 4) * 4 + r;
                atomicAdd(&sums[row], aa);
                atomicAdd(&sums[NROWS + row], ss);
            }
        }
    }
}

// ---- finalize + positive-pair correction, 8 threads per row (1024 waves).
//      (byte-identical to the round-7/8 verified kernel) ----
__global__ void finalize_kernel(const _Float16* __restrict__ xf,
                                const float* __restrict__ sums,
                                float* __restrict__ out) {
    const int tid = threadIdx.x;
    const int i = blockIdx.x * 32 + (tid >> 3);   // row
    const int j = tid & 7;                        // partner slot
    const int g = i >> 4, ri = i & 15, ii = i & 7;
    const _Float16* base = xf + (size_t)g * 2048;

    float pL = 0.f, pS = 0.f, subL = 0.f, subS = 0.f;
    if (j != ii) {
        const int rj = ri - ii + j;               // same 16-row group (classes 8-aligned)
        float dot = 0.f;
        #pragma unroll
        for (int kk = 0; kk < 4; ++kk) {
            #pragma unroll
            for (int h = 0; h < 4; ++h) {
                f16x8 av = *(const f16x8*)(base + kk * 512 + ((h << 4) | ri) * 8);
                f16x8 bv = *(const f16x8*)(base + kk * 512 + ((h << 4) | rj) * 8);
#if HAVE_FDOT2
                #pragma unroll
                for (int u = 0; u < 4; ++u) {
                    f16x2 pa = { av[2 * u], av[2 * u + 1] };
                    f16x2 pb = { bv[2 * u], bv[2 * u + 1] };
                    dot = __builtin_amdgcn_fdot2(pa, pb, dot, false);
                }
#else
                #pragma unroll
                for (int u = 0; u < 8; ++u)
                    dot = fmaf((float)av[u], (float)bv[u], dot);
#endif
            }
        }
        float d2 = fmaf(-2.f, dot, 2.f);
        float d  = sqrtf(fmaxf(d2, 1e-12f));           // reference clamp
        float tt = __builtin_amdgcn_exp2f(-d * K20);   // exp(-20 d)
        pS = __builtin_amdgcn_exp2f(d * K20);          // exp(+20 d)
        pL = tt * tt;
        float tp = (d2 * K2 < DTHR) ? 0.f : tt;        // what pair_kernel added
        subS = tp;
        subL = tp * tp;
    }

    // combine the 8 partner slots of this row
    #pragma unroll
    for (int m = 1; m < 8; m <<= 1) {
        pL   += __shfl_xor(pL, m, 64);
        pS   += __shfl_xor(pS, m, 64);
        subL += __shfl_xor(subL, m, 64);
        subS += __shfl_xor(subS, m, 64);
    }

    float v = 0.f;
    if (j == 0) {
        float nLv = sums[i] - subL;
        float nSv = sums[NROWS + i] - subS;
        float aLr  = 1.0f - pL / (pL + nLv);
        float posL = logf(pS) - 16.0f;    // log(sum exp(20(d-0.8)))
        float negL = logf(nSv) + 22.0f;   // log(sum exp(20(1.1-d)))
        v = aLr * (posL + negL);
    }
    #pragma unroll
    for (int m = 8; m < 64; m <<= 1) v += __shfl_xor(v, m, 64);

    __shared__ float partial[4];
    int wv = tid >> 6, lane = tid & 63;
    if (lane == 0) partial[wv] = v;
    __syncthreads();
    if (tid == 0) {
        float s = partial[0] + partial[1] + partial[2] + partial[3];
        atomicAdd(out, s * (1.0f / NROWS));
    }
}

extern "C" void kernel_launch(void* const* d_in, const int* in_sizes, int n_in,
                              void* d_out, int out_size, void* d_ws, size_t ws_size,
                              hipStream_t stream) {
    const float* x = (const float*)d_in[0];
    float* out = (float*)d_out;

    _Float16* xf = (_Float16*)d_ws;              // 2 MB, fragment-major
    float* sums  = (float*)(xf + NROWS * DDIM);  // 2*NROWS floats

    convert_kernel<<<NROWS * DDIM / (256 * 4), 256, 0, stream>>>(x, xf, sums, out);
    dim3 grid(NROWS / 128, NROWS / 512);         // 64 x 16 = 1024 blocks, 1 generation
    pair_kernel<<<grid, 256, 0, stream>>>(xf, sums);
    finalize_kernel<<<NROWS / 32, 256, 0, stream>>>(xf, sums, out);
}